// Round 2
// baseline (33.181 us; speedup 1.0000x reference)
//
#include <hip/hip_runtime.h>
#include <hip/hip_bf16.h>

#define N_SHARD 4
#define PPP     512
#define NEG_N   1024
#define EMB     256
#define NROWS   (N_SHARD * PPP)   // 2048

typedef __attribute__((ext_vector_type(8))) short bf16x8;  // 8 bf16 (4 VGPRs)
typedef __attribute__((ext_vector_type(4))) float f32x4;   // 4 fp32 acc

__device__ __forceinline__ unsigned short f2bf(float f) {
    union { float f; unsigned int u; } v; v.f = f;
    return (unsigned short)((v.u + 0x7FFFu + ((v.u >> 16) & 1u)) >> 16);
}

// One fused kernel. Grid (32,16): block = 64 output rows x 64 neg cols.
// Phase 1: gather h,r (and t for y==0 blocks) + negatives straight from the
//          embedding tables into swizzled bf16 LDS tiles (redundant across
//          blocks, but L2-resident: per-XCD working set ~1.5 MB < 4 MB).
// Phase 2: 4 waves x (16x64) MFMA tiles from LDS, epilogue writes each value
//          to the 4 column-replicas of the (2048, 4096) output.
__global__ __launch_bounds__(256, 2) void fused_kernel(
    const int* __restrict__ head, const int* __restrict__ relation,
    const int* __restrict__ tail, const int* __restrict__ negative,
    const float* __restrict__ ent, const float* __restrict__ relemb,
    float* __restrict__ pos_out, float* __restrict__ neg_out)
{
    __shared__ unsigned short Abuf[64 * EMB];   // 32 KiB, XOR-swizzled
    __shared__ unsigned short Bbuf[64 * EMB];   // 32 KiB, XOR-swizzled

    const int wid  = threadIdx.x >> 6;
    const int lane = threadIdx.x & 63;
    const int row_tile = blockIdx.x * 64;
    const int col_tile = blockIdx.y * 64;

    // ---- Phase 1: gather ----
    // A rows (h*r), 16 rows per wave; y==0 blocks also produce positive scores.
    #pragma unroll 4
    for (int i = 0; i < 16; ++i) {
        const int r = wid * 16 + i;            // row within tile (0..63)
        const int n = row_tile + r;            // global row (0..2047)
        const int hi = head[n], ri = relation[n];
        const float4 h4 = ((const float4*)(ent    + (size_t)hi * EMB))[lane];
        const float4 r4 = ((const float4*)(relemb + (size_t)ri * EMB))[lane];
        const float x = h4.x * r4.x, y = h4.y * r4.y;
        const float z = h4.z * r4.z, w = h4.w * r4.w;
        const ushort4 s = make_ushort4(f2bf(x), f2bf(y), f2bf(z), f2bf(w));
        const int byte = r * 512 + ((lane * 8) ^ ((r & 7) << 4));
        *(ushort4*)((char*)Abuf + byte) = s;
        if (blockIdx.y == 0) {
            const int ti = tail[n];
            const float4 t4 = ((const float4*)(ent + (size_t)ti * EMB))[lane];
            float p = x * t4.x + y * t4.y + z * t4.z + w * t4.w;
            #pragma unroll
            for (int off = 32; off > 0; off >>= 1) p += __shfl_down(p, off, 64);
            if (lane == 0) pos_out[n] = p;
        }
    }
    // B rows (negative tails, shard 0 only)
    #pragma unroll 4
    for (int i = 0; i < 16; ++i) {
        const int r = wid * 16 + i;
        const int m = col_tile + r;            // global neg (0..1023)
        const int idx = negative[m];
        const float4 t4 = ((const float4*)(ent + (size_t)idx * EMB))[lane];
        const ushort4 s = make_ushort4(f2bf(t4.x), f2bf(t4.y), f2bf(t4.z), f2bf(t4.w));
        const int byte = r * 512 + ((lane * 8) ^ ((r & 7) << 4));
        *(ushort4*)((char*)Bbuf + byte) = s;
    }
    __syncthreads();

    // ---- Phase 2: MFMA ----
    const int r16  = lane & 15;
    const int half = lane >> 4;
    const int arow = wid * 16 + r16;
    const int aswz = (arow & 7) << 4;
    const int bswz = (r16 & 7) << 4;           // (nf*16 + r16)&7 == r16&7

    f32x4 acc0 = {0.f, 0.f, 0.f, 0.f};
    f32x4 acc1 = acc0, acc2 = acc0, acc3 = acc0;
    #pragma unroll
    for (int kk = 0; kk < 8; ++kk) {
        const int koff = kk * 64 + half * 16;
        const bf16x8 a = *(const bf16x8*)((const char*)Abuf + arow * 512 + (koff ^ aswz));
        const bf16x8 b0 = *(const bf16x8*)((const char*)Bbuf + (r16 +  0) * 512 + (koff ^ bswz));
        const bf16x8 b1 = *(const bf16x8*)((const char*)Bbuf + (r16 + 16) * 512 + (koff ^ bswz));
        const bf16x8 b2 = *(const bf16x8*)((const char*)Bbuf + (r16 + 32) * 512 + (koff ^ bswz));
        const bf16x8 b3 = *(const bf16x8*)((const char*)Bbuf + (r16 + 48) * 512 + (koff ^ bswz));
        acc0 = __builtin_amdgcn_mfma_f32_16x16x32_bf16(a, b0, acc0, 0, 0, 0);
        acc1 = __builtin_amdgcn_mfma_f32_16x16x32_bf16(a, b1, acc1, 0, 0, 0);
        acc2 = __builtin_amdgcn_mfma_f32_16x16x32_bf16(a, b2, acc2, 0, 0, 0);
        acc3 = __builtin_amdgcn_mfma_f32_16x16x32_bf16(a, b3, acc3, 0, 0, 0);
    }

    // ---- Epilogue: C/D layout col = lane&15, row = (lane>>4)*4 + reg ----
    const int row_base = row_tile + wid * 16 + half * 4;
    #pragma unroll
    for (int v = 0; v < 4; ++v) {
        float* orow = neg_out + (size_t)(row_base + v) * 4096;
        const float vals[4] = {acc0[v], acc1[v], acc2[v], acc3[v]};
        #pragma unroll
        for (int nf = 0; nf < 4; ++nf) {
            const int col = col_tile + nf * 16 + r16;
            const float val = vals[nf];
            orow[col]        = val;
            orow[col + 1024] = val;
            orow[col + 2048] = val;
            orow[col + 3072] = val;
        }
    }
}

extern "C" void kernel_launch(void* const* d_in, const int* in_sizes, int n_in,
                              void* d_out, int out_size, void* d_ws, size_t ws_size,
                              hipStream_t stream) {
    const int*   head     = (const int*)d_in[0];
    const int*   relation = (const int*)d_in[1];
    const int*   tail     = (const int*)d_in[2];
    const int*   negative = (const int*)d_in[3];
    const float* ent      = (const float*)d_in[4];
    const float* rel      = (const float*)d_in[5];

    float* pos_out = (float*)d_out;            // 2048
    float* neg_out = (float*)d_out + NROWS;    // 2048 * 4096

    fused_kernel<<<dim3(32, 16), 256, 0, stream>>>(head, relation, tail, negative,
                                                   ent, rel, pos_out, neg_out);
}

// Round 3
// 21.477 us; speedup vs baseline: 1.5450x; 1.5450x over previous
//
#include <hip/hip_runtime.h>
#include <hip/hip_bf16.h>

#define N_SHARD 4
#define PPP     512
#define NEG_N   1024
#define EMB     256
#define NROWS   (N_SHARD * PPP)   // 2048

typedef __attribute__((ext_vector_type(8))) short bf16x8;  // 8 bf16 (4 VGPRs)
typedef __attribute__((ext_vector_type(4))) float f32x4;   // 4 fp32 acc

__device__ __forceinline__ unsigned short f2bf(float f) {
    union { float f; unsigned int u; } v; v.f = f;
    return (unsigned short)((v.u + 0x7FFFu + ((v.u >> 16) & 1u)) >> 16);
}

// async 16B global->LDS copy (linear dest: wave-uniform base + lane*16)
__device__ __forceinline__ void load16_to_lds(const void* g, void* l) {
    __builtin_amdgcn_global_load_lds(
        (const __attribute__((address_space(1))) unsigned int*)g,
        (__attribute__((address_space(3))) unsigned int*)l, 16, 0, 0);
}

// ---------------- Kernel 1: gather + positive scores + swizzled bf16 staging ---------
// One wave per row. Staging rows are 512B, XOR-swizzled within the row by
// ((row & 7) << 4) so the GEMM's ds_read_b128 after a LINEAR global_load_lds
// copy is bank-conflict-free (T2 / m173 pattern: pre-swizzle the source).
__global__ __launch_bounds__(256) void prep_kernel(
    const int* __restrict__ head, const int* __restrict__ relation,
    const int* __restrict__ tail, const int* __restrict__ negative,
    const float* __restrict__ ent, const float* __restrict__ relemb,
    float* __restrict__ pos_out,
    unsigned short* __restrict__ hr_bf, unsigned short* __restrict__ t_bf)
{
    const int wave = blockIdx.x * 4 + (threadIdx.x >> 6);
    const int lane = threadIdx.x & 63;
    if (wave < NROWS) {
        const int n = wave;
        const int hi = head[n], ri = relation[n], ti = tail[n];
        const float4 h4 = ((const float4*)(ent    + (size_t)hi * EMB))[lane];
        const float4 r4 = ((const float4*)(relemb + (size_t)ri * EMB))[lane];
        const float4 t4 = ((const float4*)(ent    + (size_t)ti * EMB))[lane];
        const float x = h4.x * r4.x, y = h4.y * r4.y;
        const float z = h4.z * r4.z, w = h4.w * r4.w;
        const ushort4 s = make_ushort4(f2bf(x), f2bf(y), f2bf(z), f2bf(w));
        const int byte_in_row = (lane * 8) ^ ((n & 7) << 4);
        *(ushort4*)((char*)hr_bf + (size_t)n * 512 + byte_in_row) = s;
        float p = x * t4.x + y * t4.y + z * t4.z + w * t4.w;
        #pragma unroll
        for (int off = 32; off > 0; off >>= 1) p += __shfl_down(p, off, 64);
        if (lane == 0) pos_out[n] = p;
    } else if (wave < NROWS + NEG_N) {
        const int m = wave - NROWS;
        const int idx = negative[m];   // negative[0][0][m]: only shard 0 is used
        const float4 t4 = ((const float4*)(ent + (size_t)idx * EMB))[lane];
        const ushort4 s = make_ushort4(f2bf(t4.x), f2bf(t4.y), f2bf(t4.z), f2bf(t4.w));
        const int byte_in_row = (lane * 8) ^ ((m & 7) << 4);
        *(ushort4*)((char*)t_bf + (size_t)m * 512 + byte_in_row) = s;
    }
}

// ---------------- Kernel 2: 64x64-tile GEMM from LDS-staged operands ----------------
// C[n,m] = sum_k hr[n,k] * t_neg[m,k].  Grid (32,16); 4 waves stacked along M.
// A/B tiles (32 KB each) copied linearly global->LDS (content pre-swizzled by prep),
// ds_read_b128 with the same XOR -> conflict-free fragments.
__global__ __launch_bounds__(256, 2) void gemm_kernel(
    const unsigned short* __restrict__ hr_bf,
    const unsigned short* __restrict__ t_bf,
    float* __restrict__ neg_out)
{
    __shared__ unsigned short Abuf[64 * EMB];   // 32 KiB
    __shared__ unsigned short Bbuf[64 * EMB];   // 32 KiB

    const int wid  = threadIdx.x >> 6;
    const int lane = threadIdx.x & 63;
    const int row_tile = blockIdx.x * 64;
    const int col_tile = blockIdx.y * 64;

    // Stage: each wave copies 8 x 1KB chunks of each tile (64 lanes x 16B).
    const char* aSrc = (const char*)(hr_bf + (size_t)row_tile * EMB);
    const char* bSrc = (const char*)(t_bf  + (size_t)col_tile * EMB);
    #pragma unroll
    for (int c = 0; c < 8; ++c) {
        const int chunk = (wid * 8 + c) * 1024;
        const int goff  = chunk + lane * 16;
        load16_to_lds(aSrc + goff, (char*)Abuf + chunk);
        load16_to_lds(bSrc + goff, (char*)Bbuf + chunk);
    }
    __syncthreads();

    const int r16  = lane & 15;
    const int half = lane >> 4;
    const int arow = wid * 16 + r16;
    const int aswz = (arow & 7) << 4;
    const int bswz = (r16 & 7) << 4;           // rows r16+16k share (row&7)

    f32x4 acc0 = {0.f, 0.f, 0.f, 0.f};
    f32x4 acc1 = acc0, acc2 = acc0, acc3 = acc0;
    #pragma unroll
    for (int kk = 0; kk < 8; ++kk) {
        const int koff = kk * 64 + half * 16;
        const bf16x8 a  = *(const bf16x8*)((const char*)Abuf + arow * 512 + (koff ^ aswz));
        const bf16x8 b0 = *(const bf16x8*)((const char*)Bbuf + (r16 +  0) * 512 + (koff ^ bswz));
        const bf16x8 b1 = *(const bf16x8*)((const char*)Bbuf + (r16 + 16) * 512 + (koff ^ bswz));
        const bf16x8 b2 = *(const bf16x8*)((const char*)Bbuf + (r16 + 32) * 512 + (koff ^ bswz));
        const bf16x8 b3 = *(const bf16x8*)((const char*)Bbuf + (r16 + 48) * 512 + (koff ^ bswz));
        acc0 = __builtin_amdgcn_mfma_f32_16x16x32_bf16(a, b0, acc0, 0, 0, 0);
        acc1 = __builtin_amdgcn_mfma_f32_16x16x32_bf16(a, b1, acc1, 0, 0, 0);
        acc2 = __builtin_amdgcn_mfma_f32_16x16x32_bf16(a, b2, acc2, 0, 0, 0);
        acc3 = __builtin_amdgcn_mfma_f32_16x16x32_bf16(a, b3, acc3, 0, 0, 0);
    }

    // Epilogue: C/D layout col = lane&15, row = (lane>>4)*4 + reg.
    // Non-temporal: the 33.5 MB output is pure streaming, never re-read.
    const int row_base = row_tile + wid * 16 + half * 4;
    #pragma unroll
    for (int v = 0; v < 4; ++v) {
        float* orow = neg_out + (size_t)(row_base + v) * 4096;
        const float vals[4] = {acc0[v], acc1[v], acc2[v], acc3[v]};
        #pragma unroll
        for (int nf = 0; nf < 4; ++nf) {
            const int col = col_tile + nf * 16 + r16;
            const float val = vals[nf];
            __builtin_nontemporal_store(val, &orow[col]);
            __builtin_nontemporal_store(val, &orow[col + 1024]);
            __builtin_nontemporal_store(val, &orow[col + 2048]);
            __builtin_nontemporal_store(val, &orow[col + 3072]);
        }
    }
}

extern "C" void kernel_launch(void* const* d_in, const int* in_sizes, int n_in,
                              void* d_out, int out_size, void* d_ws, size_t ws_size,
                              hipStream_t stream) {
    const int*   head     = (const int*)d_in[0];
    const int*   relation = (const int*)d_in[1];
    const int*   tail     = (const int*)d_in[2];
    const int*   negative = (const int*)d_in[3];
    const float* ent      = (const float*)d_in[4];
    const float* rel      = (const float*)d_in[5];

    float* pos_out = (float*)d_out;            // 2048
    float* neg_out = (float*)d_out + NROWS;    // 2048 * 4096

    unsigned short* hr_bf = (unsigned short*)d_ws;                  // 2048*256 bf16 = 1 MiB
    unsigned short* t_bf  = hr_bf + (size_t)NROWS * EMB;            // 1024*256 bf16 = 0.5 MiB

    prep_kernel<<<768, 256, 0, stream>>>(head, relation, tail, negative, ent, rel,
                                         pos_out, hr_bf, t_bf);
    gemm_kernel<<<dim3(32, 16), 256, 0, stream>>>(hr_bf, t_bf, neg_out);
}

// Round 5
// 19.212 us; speedup vs baseline: 1.7271x; 1.1179x over previous
//
#include <hip/hip_runtime.h>
#include <hip/hip_bf16.h>

#define N_SHARD 4
#define PPP     512
#define NEG_N   1024
#define EMB     256
#define NROWS   (N_SHARD * PPP)   // 2048

typedef __attribute__((ext_vector_type(8))) short bf16x8;  // 8 bf16 (4 VGPRs)
typedef __attribute__((ext_vector_type(4))) float f32x4;   // 4 fp32 acc

__device__ __forceinline__ unsigned short f2bf(float f) {
    union { float f; unsigned int u; } v; v.f = f;
    return (unsigned short)((v.u + 0x7FFFu + ((v.u >> 16) & 1u)) >> 16);
}

// async 16B global->LDS copy (linear dest: wave-uniform base + lane*16)
__device__ __forceinline__ void load16_to_lds(const void* g, void* l) {
    __builtin_amdgcn_global_load_lds(
        (const __attribute__((address_space(1))) unsigned int*)g,
        (__attribute__((address_space(3))) unsigned int*)l, 16, 0, 0);
}

// ---------------- Kernel 1: gather + positive scores + swizzled bf16 staging ---------
// One wave per row. Staging rows are 512B, XOR-swizzled within the row by
// ((row & 7) << 4) so the GEMM's ds_read_b128 after a LINEAR global_load_lds
// copy is bank-conflict-free (T2 / m173 pattern: pre-swizzle the source).
__global__ __launch_bounds__(256) void prep_kernel(
    const int* __restrict__ head, const int* __restrict__ relation,
    const int* __restrict__ tail, const int* __restrict__ negative,
    const float* __restrict__ ent, const float* __restrict__ relemb,
    float* __restrict__ pos_out,
    unsigned short* __restrict__ hr_bf, unsigned short* __restrict__ t_bf)
{
    const int wave = blockIdx.x * 4 + (threadIdx.x >> 6);
    const int lane = threadIdx.x & 63;
    if (wave < NROWS) {
        const int n = wave;
        const int hi = head[n], ri = relation[n], ti = tail[n];
        const float4 h4 = ((const float4*)(ent    + (size_t)hi * EMB))[lane];
        const float4 r4 = ((const float4*)(relemb + (size_t)ri * EMB))[lane];
        const float4 t4 = ((const float4*)(ent    + (size_t)ti * EMB))[lane];
        const float x = h4.x * r4.x, y = h4.y * r4.y;
        const float z = h4.z * r4.z, w = h4.w * r4.w;
        const ushort4 s = make_ushort4(f2bf(x), f2bf(y), f2bf(z), f2bf(w));
        const int byte_in_row = (lane * 8) ^ ((n & 7) << 4);
        *(ushort4*)((char*)hr_bf + (size_t)n * 512 + byte_in_row) = s;
        float p = x * t4.x + y * t4.y + z * t4.z + w * t4.w;
        #pragma unroll
        for (int off = 32; off > 0; off >>= 1) p += __shfl_down(p, off, 64);
        if (lane == 0) pos_out[n] = p;
    } else if (wave < NROWS + NEG_N) {
        const int m = wave - NROWS;
        const int idx = negative[m];   // negative[0][0][m]: only shard 0 is used
        const float4 t4 = ((const float4*)(ent + (size_t)idx * EMB))[lane];
        const ushort4 s = make_ushort4(f2bf(t4.x), f2bf(t4.y), f2bf(t4.z), f2bf(t4.w));
        const int byte_in_row = (lane * 8) ^ ((m & 7) << 4);
        *(ushort4*)((char*)t_bf + (size_t)m * 512 + byte_in_row) = s;
    }
}

// ---------------- Kernel 2: 64x64-tile GEMM from LDS-staged operands ----------------
// C[n,m] = sum_k hr[n,k] * t_neg[m,k].  Grid (32,16); 4 waves stacked along M.
// A/B tiles (32 KB each) copied linearly global->LDS (content pre-swizzled by prep),
// ds_read_b128 with the same XOR -> conflict-free fragments.
// Epilogue: intra-wave transpose of the wave's own 16x64 C-quadrant through its
// (now dead) A-tile LDS slice -> float4 stores, 256 B contiguous per 16 lanes.
__global__ __launch_bounds__(256, 2) void gemm_kernel(
    const unsigned short* __restrict__ hr_bf,
    const unsigned short* __restrict__ t_bf,
    float* __restrict__ neg_out)
{
    __shared__ unsigned short Abuf[64 * EMB];   // 32 KiB
    __shared__ unsigned short Bbuf[64 * EMB];   // 32 KiB

    const int wid  = threadIdx.x >> 6;
    const int lane = threadIdx.x & 63;
    const int row_tile = blockIdx.x * 64;
    const int col_tile = blockIdx.y * 64;

    // Stage: each wave copies 8 x 1KB chunks of each tile (64 lanes x 16B).
    const char* aSrc = (const char*)(hr_bf + (size_t)row_tile * EMB);
    const char* bSrc = (const char*)(t_bf  + (size_t)col_tile * EMB);
    #pragma unroll
    for (int c = 0; c < 8; ++c) {
        const int chunk = (wid * 8 + c) * 1024;
        const int goff  = chunk + lane * 16;
        load16_to_lds(aSrc + goff, (char*)Abuf + chunk);
        load16_to_lds(bSrc + goff, (char*)Bbuf + chunk);
    }
    __syncthreads();

    const int r16  = lane & 15;
    const int half = lane >> 4;
    const int arow = wid * 16 + r16;
    const int aswz = (arow & 7) << 4;
    const int bswz = (r16 & 7) << 4;           // rows r16+16k share (row&7)

    f32x4 acc0 = {0.f, 0.f, 0.f, 0.f};
    f32x4 acc1 = acc0, acc2 = acc0, acc3 = acc0;
    #pragma unroll
    for (int kk = 0; kk < 8; ++kk) {
        const int koff = kk * 64 + half * 16;
        const bf16x8 a  = *(const bf16x8*)((const char*)Abuf + arow * 512 + (koff ^ aswz));
        const bf16x8 b0 = *(const bf16x8*)((const char*)Bbuf + (r16 +  0) * 512 + (koff ^ bswz));
        const bf16x8 b1 = *(const bf16x8*)((const char*)Bbuf + (r16 + 16) * 512 + (koff ^ bswz));
        const bf16x8 b2 = *(const bf16x8*)((const char*)Bbuf + (r16 + 32) * 512 + (koff ^ bswz));
        const bf16x8 b3 = *(const bf16x8*)((const char*)Bbuf + (r16 + 48) * 512 + (koff ^ bswz));
        acc0 = __builtin_amdgcn_mfma_f32_16x16x32_bf16(a, b0, acc0, 0, 0, 0);
        acc1 = __builtin_amdgcn_mfma_f32_16x16x32_bf16(a, b1, acc1, 0, 0, 0);
        acc2 = __builtin_amdgcn_mfma_f32_16x16x32_bf16(a, b2, acc2, 0, 0, 0);
        acc3 = __builtin_amdgcn_mfma_f32_16x16x32_bf16(a, b3, acc3, 0, 0, 0);
    }

    // ---- Epilogue: intra-wave LDS transpose, then coalesced float4 stores ----
    // Wave wid's C-quadrant is rows [wid*16, wid*16+16) x all 64 cols — exactly
    // the rows of the A-slice only THIS wave read. Reuse that 8 KB slice (needs
    // 4 KB) with no barrier: acc data-dependency orders reads before writes.
    // MFMA C/D layout: col = nf*16 + (lane&15), local row = (lane>>4)*4 + v.
    // Bank swizzle: col ^= ((lrow>>2)&3)<<4  (2-way max aliasing = free).
    float* cw = (float*)((char*)Abuf + wid * 8192);
    #pragma unroll
    for (int v = 0; v < 4; ++v) {
        const int lr = half * 4 + v;
        const float vals[4] = {acc0[v], acc1[v], acc2[v], acc3[v]};
        #pragma unroll
        for (int nf = 0; nf < 4; ++nf) {
            const int c = nf * 16 + r16;
            cw[lr * 64 + (c ^ (half << 4))] = vals[nf];
        }
    }
    #pragma unroll
    for (int j = 0; j < 4; ++j) {
        const int lr = j * 4 + half;                       // (lr>>2)&3 == j
        const f32x4 v4 = *(const f32x4*)&cw[lr * 64 + ((r16 * 4) ^ (j << 4))];
        const int grow = row_tile + wid * 16 + lr;
        float* orow = neg_out + (size_t)grow * 4096 + col_tile + r16 * 4;
        __builtin_nontemporal_store(v4, (f32x4*)(orow));
        __builtin_nontemporal_store(v4, (f32x4*)(orow + 1024));
        __builtin_nontemporal_store(v4, (f32x4*)(orow + 2048));
        __builtin_nontemporal_store(v4, (f32x4*)(orow + 3072));
    }
}

extern "C" void kernel_launch(void* const* d_in, const int* in_sizes, int n_in,
                              void* d_out, int out_size, void* d_ws, size_t ws_size,
                              hipStream_t stream) {
    const int*   head     = (const int*)d_in[0];
    const int*   relation = (const int*)d_in[1];
    const int*   tail     = (const int*)d_in[2];
    const int*   negative = (const int*)d_in[3];
    const float* ent      = (const float*)d_in[4];
    const float* rel      = (const float*)d_in[5];

    float* pos_out = (float*)d_out;            // 2048
    float* neg_out = (float*)d_out + NROWS;    // 2048 * 4096

    unsigned short* hr_bf = (unsigned short*)d_ws;                  // 2048*256 bf16 = 1 MiB
    unsigned short* t_bf  = hr_bf + (size_t)NROWS * EMB;            // 1024*256 bf16 = 0.5 MiB

    prep_kernel<<<768, 256, 0, stream>>>(head, relation, tail, negative, ent, rel,
                                         pos_out, hr_bf, t_bf);
    gemm_kernel<<<dim3(32, 16), 256, 0, stream>>>(hr_bf, t_bf, neg_out);
}

// Round 10
// 18.225 us; speedup vs baseline: 1.8206x; 1.0542x over previous
//
#include <hip/hip_runtime.h>
#include <hip/hip_bf16.h>

#define N_SHARD 4
#define PPP     512
#define NEG_N   1024
#define EMB     256
#define NROWS   (N_SHARD * PPP)   // 2048

typedef __attribute__((ext_vector_type(8))) short bf16x8;  // 8 bf16 (4 VGPRs)
typedef __attribute__((ext_vector_type(4))) float f32x4;   // 4 fp32 acc

__device__ __forceinline__ unsigned short f2bf(float f) {
    union { float f; unsigned int u; } v; v.f = f;
    return (unsigned short)((v.u + 0x7FFFu + ((v.u >> 16) & 1u)) >> 16);
}

// ONE kernel, NO workspace, NO cross-block dependency (r6-r9 post-mortem:
// ws-mediated producer->consumer never becomes visible across blocks on this
// stack regardless of fence scope/barrier mechanism — so eliminate it).
// Grid 256 x 512 threads. Block (p = bx&31, q = bx>>5): output rows p*64..+64,
// col-pair q*128..+128. Gathers its own operands straight from the embedding
// tables into swizzled LDS. bx%8 == p%8 -> all 8 q-blocks sharing an A-panel
// live on one XCD: A fetched once per XCD, then L2-hits (working set ~1.5MB).
// q==0 blocks additionally produce the positive scores.
__global__ __launch_bounds__(512, 1) void fused_kernel(
    const int* __restrict__ head, const int* __restrict__ relation,
    const int* __restrict__ tail, const int* __restrict__ negative,
    const float* __restrict__ ent, const float* __restrict__ relemb,
    float* __restrict__ pos_out, float* __restrict__ neg_out)
{
    __shared__ unsigned short Abuf[64 * EMB];    // 32 KiB, XOR-swizzled
    __shared__ unsigned short Bbuf[128 * EMB];   // 64 KiB, XOR-swizzled
    __shared__ int idxbuf[64 * 3 + 128];         // 1.25 KiB

    const int tid  = threadIdx.x;
    const int wid  = tid >> 6;        // 0..7
    const int lane = tid & 63;
    const int p    = blockIdx.x & 31;
    const int q    = blockIdx.x >> 5; // 0..7
    const int row0 = p * 64;
    const int colp = q * 128;

    int* hIdx = idxbuf;               // 64
    int* rIdx = idxbuf + 64;          // 64
    int* tIdx = idxbuf + 128;         // 64 (q==0 only)
    int* nIdx = idxbuf + 192;         // 128

    // ---- Phase 0: coalesced index preload (kills idx->row latency chains) ----
    if (tid < 64)            hIdx[tid]       = head[row0 + tid];
    else if (tid < 128)      rIdx[tid - 64]  = relation[row0 + tid - 64];
    else if (tid < 256)      nIdx[tid - 128] = negative[colp + tid - 128]; // shard 0
    else if (tid < 320 && q == 0) tIdx[tid - 256] = tail[row0 + tid - 256];
    __syncthreads();

    // ---- Phase 1: A gather (wave w -> rows w*8..+8). hr product -> bf16 LDS ----
    #pragma unroll
    for (int i = 0; i < 8; ++i) {
        const int r = wid * 8 + i;
        const float4 h4 = ((const float4*)(ent    + (size_t)hIdx[r] * EMB))[lane];
        const float4 r4 = ((const float4*)(relemb + (size_t)rIdx[r] * EMB))[lane];
        const float x = h4.x * r4.x, y = h4.y * r4.y;
        const float z = h4.z * r4.z, w = h4.w * r4.w;
        const ushort4 s = make_ushort4(f2bf(x), f2bf(y), f2bf(z), f2bf(w));
        *(ushort4*)((char*)Abuf + r * 512 + ((lane * 8) ^ ((r & 7) << 4))) = s;
        if (q == 0) {
            const float4 t4 = ((const float4*)(ent + (size_t)tIdx[r] * EMB))[lane];
            float pd = x * t4.x + y * t4.y + z * t4.z + w * t4.w;
            #pragma unroll
            for (int off = 32; off > 0; off >>= 1) pd += __shfl_down(pd, off, 64);
            if (lane == 0) pos_out[row0 + r] = pd;
        }
    }
    // ---- Phase 1b: B gather (wave w -> rows w*16..+16) ----
    #pragma unroll
    for (int i = 0; i < 16; ++i) {
        const int m = wid * 16 + i;
        const float4 t4 = ((const float4*)(ent + (size_t)nIdx[m] * EMB))[lane];
        const ushort4 s = make_ushort4(f2bf(t4.x), f2bf(t4.y), f2bf(t4.z), f2bf(t4.w));
        *(ushort4*)((char*)Bbuf + m * 512 + ((lane * 8) ^ ((m & 7) << 4))) = s;
    }
    __syncthreads();

    // ---- Phase 2: MFMA. wave (wr = wid>>1, wc = wid&1): 16 rows x 64 cols ----
    const int r16  = lane & 15;
    const int half = lane >> 4;
    const int wr   = wid >> 1, wc = wid & 1;
    const int arow = wr * 16 + r16;
    const int aswz = (arow & 7) << 4;
    const int bb   = wc * 64;                  // B row base; (bb+nf*16)%8 == 0
    const int bswz = (r16 & 7) << 4;

    f32x4 acc[4];
    #pragma unroll
    for (int nf = 0; nf < 4; ++nf) acc[nf] = (f32x4){0.f, 0.f, 0.f, 0.f};

    #pragma unroll
    for (int kk = 0; kk < 8; ++kk) {
        const int koff = kk * 64 + half * 16;
        const bf16x8 a = *(const bf16x8*)((const char*)Abuf + arow * 512 + (koff ^ aswz));
        #pragma unroll
        for (int nf = 0; nf < 4; ++nf) {
            const bf16x8 b = *(const bf16x8*)((const char*)Bbuf + (bb + nf * 16 + r16) * 512 + (koff ^ bswz));
            acc[nf] = __builtin_amdgcn_mfma_f32_16x16x32_bf16(a, b, acc[nf], 0, 0, 0);
        }
    }
    __syncthreads();   // A-rows are read by TWO col-waves: all MFMAs done before scratch reuse

    // ---- Epilogue: intra-wave LDS transpose (4KB scratch slice per wave in
    //      the dead A-buf), then coalesced NT float4 stores x4 replicas ----
    float* cw = (float*)((char*)Abuf + wid * 4096);
    #pragma unroll
    for (int v = 0; v < 4; ++v) {
        const int lr = half * 4 + v;
        #pragma unroll
        for (int nf = 0; nf < 4; ++nf) {
            const int c = nf * 16 + r16;
            cw[lr * 64 + (c ^ (half << 4))] = acc[nf][v];
        }
    }
    #pragma unroll
    for (int j = 0; j < 4; ++j) {
        const int lr = j * 4 + half;
        const f32x4 v4 = *(const f32x4*)&cw[lr * 64 + ((r16 * 4) ^ (j << 4))];
        const int grow = row0 + wr * 16 + lr;
        float* orow = neg_out + (size_t)grow * 4096 + colp + wc * 64 + r16 * 4;
        __builtin_nontemporal_store(v4, (f32x4*)(orow));
        __builtin_nontemporal_store(v4, (f32x4*)(orow + 1024));
        __builtin_nontemporal_store(v4, (f32x4*)(orow + 2048));
        __builtin_nontemporal_store(v4, (f32x4*)(orow + 3072));
    }
}

extern "C" void kernel_launch(void* const* d_in, const int* in_sizes, int n_in,
                              void* d_out, int out_size, void* d_ws, size_t ws_size,
                              hipStream_t stream) {
    const int*   head     = (const int*)d_in[0];
    const int*   relation = (const int*)d_in[1];
    const int*   tail     = (const int*)d_in[2];
    const int*   negative = (const int*)d_in[3];
    const float* ent      = (const float*)d_in[4];
    const float* rel      = (const float*)d_in[5];

    float* pos_out = (float*)d_out;            // 2048
    float* neg_out = (float*)d_out + NROWS;    // 2048 * 4096

    fused_kernel<<<256, 512, 0, stream>>>(head, relation, tail, negative,
                                          ent, rel, pos_out, neg_out);
}